// Round 10
// baseline (158.834 us; speedup 1.0000x reference)
//
#include <hip/hip_runtime.h>

// Problem constants (match reference file)
constexpr int   NUM_CLAUSES = 1000000;
constexpr int   NUM_EDGES   = 3000000;   // per polarity
constexpr float Pc = 5.0f;
constexpr float Ac = 10.0f;

// Clause-accumulator packing: low 16 bits = num * 2^6, high 16 = den * 2^6.
// Exactly 3 pos + 3 neg edges per clause; each term <= e^5 = 148.413 ->
// max field sum 6*148.413*64 = 56,990 < 65,536: no overflow, no lo->hi carry.
constexpr float FXSCALE = 64.0f;
constexpr float FXINV   = 1.0f / 64.0f;

// Bucketing: 250 buckets x 4000 clauses.
constexpr int NB  = 250;
constexpr int CPB = 4000;            // clauses per bucket (fits 12 bits)

// Partition geometry: 512 threads, 8192 records per block, 16 per thread.
constexpr int TPB   = 512;
constexpr int RPB   = 8192;
constexpr int RPT   = RPB / TPB;     // 16
constexpr int NBLKP = (NUM_EDGES + RPB - 1) / RPB;   // 367 blocks / polarity
constexpr int NBLK  = 2 * NBLKP;     // 734 partition blocks total
constexpr int TW    = NB + 1;        // segment-table row width (251)

// Record format (u32): lit quantized to 20 bits << 12 | local clause (12 bits).
// Polarity already applied to lit, so pos/neg records are interchangeable.
constexpr float QSCALE = 1048575.0f;    // 2^20 - 1
constexpr float QINV   = 1.0f / 1048575.0f;

// Workspace layout (bytes):
//   recs u32[NBLK*RPB]  = 24,051,712  @ 0        (block-major, bucket-sorted)
//   tab  u32[NBLK*TW]   =    736,936  @ OFF_TAB  (per-block exclusive scans)
//   partials f32[NB]                  @ OFF_PAR
constexpr size_t OFF_TAB = (size_t)NBLK * RPB * sizeof(unsigned);
constexpr size_t OFF_PAR = OFF_TAB + (size_t)NBLK * TW * sizeof(unsigned);

__device__ __forceinline__ unsigned pack_fx(float num, float den) {
    unsigned lo = (unsigned)(num * FXSCALE + 0.5f);
    unsigned hi = (unsigned)(den * FXSCALE + 0.5f);
    return lo | (hi << 16);
}

// ---------------------------------------------------------------------------
// Partition BOTH polarities' 6M edge records into per-block bucket-sorted
// runs. NO GLOBAL ATOMICS: block g writes its records to recs[g*RPB ...]
// (fully sequential) and its 251-entry local exclusive scan to tab[g*TW ...].
// ---------------------------------------------------------------------------
__global__ __launch_bounds__(TPB)
void partition_kernel(const int*   __restrict__ adj_pos,
                      const int*   __restrict__ adj_neg,
                      const float* __restrict__ x,
                      unsigned* __restrict__ recs,
                      unsigned* __restrict__ tab) {
    __shared__ unsigned hist[NB];
    __shared__ unsigned lbase[TW];     // local exclusive scan (+ total at [NB])
    __shared__ unsigned srec[RPB];     // 32 KB staging, bucket-sorted
    __shared__ unsigned wsum[TPB / 64];
    __shared__ unsigned woff[TPB / 64];

    const int  g     = (int)blockIdx.x;
    const bool neg   = (g >= NBLKP);
    const int  sblk  = neg ? g - NBLKP : g;
    const int  start = sblk * RPB;
    const int  n     = min(RPB, NUM_EDGES - start);
    const int* crow  = neg ? adj_neg : adj_pos;
    const int* vrow  = crow + NUM_EDGES;
    const int  tid   = (int)threadIdx.x;

    for (int b = tid; b < NB; b += TPB) hist[b] = 0;
    __syncthreads();

    // ---- Pass A: load adjacency (vectorized), gather x, build records ----
    int cc_[RPT], vv_[RPT];
    if (n == RPB) {
        #pragma unroll
        for (int j = 0; j < RPT / 4; ++j) {
            int4 c4 = ((const int4*)(crow + start))[j * TPB + tid];
            int4 v4 = ((const int4*)(vrow + start))[j * TPB + tid];
            cc_[4*j] = c4.x; cc_[4*j+1] = c4.y; cc_[4*j+2] = c4.z; cc_[4*j+3] = c4.w;
            vv_[4*j] = v4.x; vv_[4*j+1] = v4.y; vv_[4*j+2] = v4.z; vv_[4*j+3] = v4.w;
        }
    } else {
        #pragma unroll
        for (int r = 0; r < RPT; ++r) {
            int pos = 4 * ((r >> 2) * TPB + tid) + (r & 3);
            cc_[r] = (pos < n) ? crow[start + pos] : -1;
            vv_[r] = (pos < n) ? vrow[start + pos] : 0;
        }
    }

    float xv[RPT];
    #pragma unroll
    for (int r = 0; r < RPT; ++r) xv[r] = x[vv_[r]];

    unsigned rec[RPT], meta[RPT];   // meta = b<<13 | rank (0xFFFFFFFF inactive)
    #pragma unroll
    for (int r = 0; r < RPT; ++r) {
        meta[r] = 0xFFFFFFFFu;
        if (cc_[r] >= 0) {
            int   c   = cc_[r];
            int   b   = c / CPB;
            float lit = neg ? (1.0f - xv[r]) : xv[r];
            unsigned q = (unsigned)(lit * QSCALE + 0.5f);
            rec[r] = (q << 12) | (unsigned)(c - b * CPB);
            unsigned rank = atomicAdd(&hist[b], 1u);   // rank within block
            meta[r] = ((unsigned)b << 13) | rank;
        }
    }
    __syncthreads();

    // ---- block-local exclusive scan of hist (wave shuffles) ----
    unsigned h    = (tid < NB) ? hist[tid] : 0u;
    unsigned incl = h;
    #pragma unroll
    for (int off = 1; off < 64; off <<= 1) {
        unsigned t = __shfl_up(incl, off, 64);
        if ((tid & 63) >= off) incl += t;
    }
    if ((tid & 63) == 63) wsum[tid >> 6] = incl;
    __syncthreads();
    if (tid == 0) {
        unsigned a = 0;
        #pragma unroll
        for (int w = 0; w < TPB / 64; ++w) { woff[w] = a; a += wsum[w]; }
    }
    __syncthreads();
    if (tid < NB) lbase[tid] = incl - h + woff[tid >> 6];
    if (tid == 0) lbase[NB] = (unsigned)n;
    __syncthreads();

    // ---- Pass B: stage records into LDS, bucket-sorted ----
    #pragma unroll
    for (int r = 0; r < RPT; ++r) {
        if (meta[r] != 0xFFFFFFFFu) {
            unsigned b    = meta[r] >> 13;
            unsigned rank = meta[r] & 0x1FFFu;
            srec[lbase[b] + rank] = rec[r];
        }
    }
    __syncthreads();

    // ---- Pass C: fully sequential writeout of records + segment table ----
    unsigned* gout = recs + (size_t)g * RPB;
    for (int p = tid; p < n; p += TPB) gout[p] = srec[p];
    unsigned* trow = tab + (size_t)g * TW;
    for (int b = tid; b < TW; b += TPB) trow[b] = lbase[b];
}

// ---------------------------------------------------------------------------
// Bucket phase: one block per bucket. For each partition block, read this
// bucket's segment (one wave per segment, start/end = adjacent table words),
// recompute w = exp(P*lit), accumulate packed (num,den) via LDS atomics,
// then decode, sigmoid + squared error, block-reduce, plain-store partial.
// ---------------------------------------------------------------------------
__global__ __launch_bounds__(1024)
void bucket_loss_kernel(const unsigned* __restrict__ recs,
                        const unsigned* __restrict__ tab,
                        const float* __restrict__ cc,
                        float* __restrict__ partials) {
    __shared__ unsigned lacc[CPB];   // 16 KB
    const int b    = (int)blockIdx.x;
    const int lane = (int)threadIdx.x & 63;
    const int wid  = (int)threadIdx.x >> 6;

    for (int j = threadIdx.x; j < CPB; j += 1024) lacc[j] = 0;
    __syncthreads();

    // one wave per partition-block segment
    for (int blk = wid; blk < NBLK; blk += 16) {
        const unsigned* trow = tab + (size_t)blk * TW + b;
        unsigned s = trow[0];
        unsigned e = trow[1];
        const unsigned* rr = recs + (size_t)blk * RPB;
        for (unsigned k = s + (unsigned)lane; k < e; k += 64) {
            unsigned r   = rr[k];
            float    lit = (float)(r >> 12) * QINV;
            float    w   = __expf(Pc * lit);
            atomicAdd(&lacc[r & 0xFFFu], pack_fx(lit * w, w));
        }
    }
    __syncthreads();

    float v = 0.0f;
    const float* gc = cc + (size_t)b * CPB;
    for (int j = threadIdx.x; j < CPB; j += 1024) {
        unsigned a   = lacc[j];                 // packed fields can't overflow
        float    num = (float)(a & 0xffffu) * FXINV;
        float    den = (float)(a >> 16)     * FXINV;
        float    sm  = 1.0f / (1.0f + __expf(-Ac * (num / den - 0.5f)));
        float    e0  = sm - gc[j];
        v += e0 * e0;
    }
    v *= 1.0f / (float)NUM_CLAUSES;

    #pragma unroll
    for (int off = 32; off > 0; off >>= 1)
        v += __shfl_down(v, off, 64);

    __shared__ float partial[16];   // 1024 threads = 16 waves
    if (lane == 0) partial[wid] = v;
    __syncthreads();
    if (threadIdx.x == 0) {
        float s = 0.f;
        #pragma unroll
        for (int w = 0; w < 16; ++w) s += partial[w];
        partials[b] = s;
    }
}

// ---------------------------------------------------------------------------
// Final reduce: ONE block sums NB partials, plain-stores out[0].
// ---------------------------------------------------------------------------
__global__ void final_kernel(const float* __restrict__ partials,
                             float* __restrict__ out, int n) {
    float v = 0.0f;
    for (int i = threadIdx.x; i < n; i += 256) v += partials[i];

    #pragma unroll
    for (int off = 32; off > 0; off >>= 1)
        v += __shfl_down(v, off, 64);

    __shared__ float partial[4];
    int lane = threadIdx.x & 63;
    int wid  = threadIdx.x >> 6;
    if (lane == 0) partial[wid] = v;
    __syncthreads();
    if (threadIdx.x == 0)
        out[0] = partial[0] + partial[1] + partial[2] + partial[3];
}

// ---------------------------------------------------------------------------
extern "C" void kernel_launch(void* const* d_in, const int* in_sizes, int n_in,
                              void* d_out, int out_size, void* d_ws, size_t ws_size,
                              hipStream_t stream) {
    const float* xv      = (const float*)d_in[0];   // [V] fp32
    const int*   adj_pos = (const int*)  d_in[1];   // [2,E] int32
    const int*   adj_neg = (const int*)  d_in[2];   // [2,E] int32
    const float* cc      = (const float*)d_in[3];   // [C] fp32 (ones)

    char* ws = (char*)d_ws;
    unsigned* recs     = (unsigned*)ws;
    unsigned* tab      = (unsigned*)(ws + OFF_TAB);
    float*    partials = (float*)   (ws + OFF_PAR);
    float*    out      = (float*)d_out;

    // 1) partition both polarities into per-block bucket-sorted runs
    //    (no global atomics; everything it writes is fully overwritten)
    partition_kernel<<<NBLK, TPB, 0, stream>>>(adj_pos, adj_neg, xv, recs, tab);

    // 2) per-bucket segment-gather + LDS accumulate + loss -> one partial each
    bucket_loss_kernel<<<NB, 1024, 0, stream>>>(recs, tab, cc, partials);

    // 3) single-block final reduce -> out[0]
    final_kernel<<<1, 256, 0, stream>>>(partials, out, NB);
}

// Round 11
// 147.294 us; speedup vs baseline: 1.0783x; 1.0783x over previous
//
#include <hip/hip_runtime.h>

// Problem constants (match reference file)
constexpr int   NUM_CLAUSES = 1000000;
constexpr int   NUM_EDGES   = 3000000;   // per polarity
constexpr float Pc = 5.0f;
constexpr float Ac = 10.0f;

// Clause-accumulator packing: low 16 bits = num * 2^6, high 16 = den * 2^6.
// Exactly 3 pos + 3 neg edges per clause; each term <= e^5 = 148.413 ->
// max field sum 6*148.413*64 = 56,990 < 65,536: no overflow, no lo->hi carry.
constexpr float FXSCALE = 64.0f;
constexpr float FXINV   = 1.0f / 64.0f;

// Bucketing: 250 buckets x 4000 clauses.
constexpr int NB  = 250;
constexpr int CPB = 4000;            // clauses per bucket (fits 12 bits)

// Partition geometry: 512 threads, 8192 records per block, 16 per thread.
constexpr int TPB   = 512;
constexpr int RPB   = 8192;
constexpr int RPT   = RPB / TPB;     // 16
constexpr int NBLKP = (NUM_EDGES + RPB - 1) / RPB;   // 367 blocks / polarity
constexpr int NBLK  = 2 * NBLKP;     // 734 partition blocks total
constexpr int TW    = NB + 1;        // table rows (251: scan + total)

// Record format (u32): lit quantized to 20 bits << 12 | local clause (12 bits).
// Polarity already applied to lit, so pos/neg records are interchangeable.
constexpr float QSCALE = 1048575.0f;    // 2^20 - 1
constexpr float QINV   = 1.0f / 1048575.0f;

// Workspace layout (bytes):
//   recs u32[NBLK*RPB]   = 24,051,712  @ 0        (block-major, bucket-sorted)
//   tabT u32[TW*NBLK]    =    736,936  @ OFF_TAB  (TRANSPOSED: row b = all
//                                                  blocks' scan value for b)
constexpr size_t OFF_TAB = (size_t)NBLK * RPB * sizeof(unsigned);

__device__ __forceinline__ unsigned pack_fx(float num, float den) {
    unsigned lo = (unsigned)(num * FXSCALE + 0.5f);
    unsigned hi = (unsigned)(den * FXSCALE + 0.5f);
    return lo | (hi << 16);
}

// ---------------------------------------------------------------------------
// Partition BOTH polarities' 6M edge records into per-block bucket-sorted
// runs. NO GLOBAL ATOMICS: block g writes its records to recs[g*RPB ...]
// (fully sequential uint4 stores) and its 251-entry local exclusive scan to
// COLUMN g of the transposed table tabT.
// Block 0 additionally zeroes out[0] (bucket kernel accumulates into it).
// ---------------------------------------------------------------------------
__global__ __launch_bounds__(TPB)
void partition_kernel(const int*   __restrict__ adj_pos,
                      const int*   __restrict__ adj_neg,
                      const float* __restrict__ x,
                      unsigned* __restrict__ recs,
                      unsigned* __restrict__ tabT,
                      float* __restrict__ out) {
    __shared__ unsigned hist[NB];
    __shared__ unsigned lbase[TW];     // local exclusive scan (+ total at [NB])
    __shared__ unsigned srec[RPB];     // 32 KB staging, bucket-sorted
    __shared__ unsigned wsum[TPB / 64];
    __shared__ unsigned woff[TPB / 64];

    const int  g     = (int)blockIdx.x;
    const bool neg   = (g >= NBLKP);
    const int  sblk  = neg ? g - NBLKP : g;
    const int  start = sblk * RPB;
    const int  n     = min(RPB, NUM_EDGES - start);
    const int* crow  = neg ? adj_neg : adj_pos;
    const int* vrow  = crow + NUM_EDGES;
    const int  tid   = (int)threadIdx.x;

    if (g == 0 && tid == 0) out[0] = 0.0f;   // bucket kernel atomic-accumulates

    for (int b = tid; b < NB; b += TPB) hist[b] = 0;
    __syncthreads();

    // ---- Pass A: load adjacency (vectorized), gather x, build records ----
    int cc_[RPT], vv_[RPT];
    if (n == RPB) {
        #pragma unroll
        for (int j = 0; j < RPT / 4; ++j) {
            int4 c4 = ((const int4*)(crow + start))[j * TPB + tid];
            int4 v4 = ((const int4*)(vrow + start))[j * TPB + tid];
            cc_[4*j] = c4.x; cc_[4*j+1] = c4.y; cc_[4*j+2] = c4.z; cc_[4*j+3] = c4.w;
            vv_[4*j] = v4.x; vv_[4*j+1] = v4.y; vv_[4*j+2] = v4.z; vv_[4*j+3] = v4.w;
        }
    } else {
        #pragma unroll
        for (int r = 0; r < RPT; ++r) {
            int pos = 4 * ((r >> 2) * TPB + tid) + (r & 3);
            cc_[r] = (pos < n) ? crow[start + pos] : -1;
            vv_[r] = (pos < n) ? vrow[start + pos] : 0;
        }
    }

    float xv[RPT];
    #pragma unroll
    for (int r = 0; r < RPT; ++r) xv[r] = x[vv_[r]];

    unsigned rec[RPT], meta[RPT];   // meta = b<<13 | rank (0xFFFFFFFF inactive)
    #pragma unroll
    for (int r = 0; r < RPT; ++r) {
        meta[r] = 0xFFFFFFFFu;
        if (cc_[r] >= 0) {
            int   c   = cc_[r];
            int   b   = c / CPB;
            float lit = neg ? (1.0f - xv[r]) : xv[r];
            unsigned q = (unsigned)(lit * QSCALE + 0.5f);
            rec[r] = (q << 12) | (unsigned)(c - b * CPB);
            unsigned rank = atomicAdd(&hist[b], 1u);   // rank within block
            meta[r] = ((unsigned)b << 13) | rank;
        }
    }
    __syncthreads();

    // ---- block-local exclusive scan of hist (wave shuffles) ----
    unsigned h    = (tid < NB) ? hist[tid] : 0u;
    unsigned incl = h;
    #pragma unroll
    for (int off = 1; off < 64; off <<= 1) {
        unsigned t = __shfl_up(incl, off, 64);
        if ((tid & 63) >= off) incl += t;
    }
    if ((tid & 63) == 63) wsum[tid >> 6] = incl;
    __syncthreads();
    if (tid == 0) {
        unsigned a = 0;
        #pragma unroll
        for (int w = 0; w < TPB / 64; ++w) { woff[w] = a; a += wsum[w]; }
    }
    __syncthreads();
    if (tid < NB) lbase[tid] = incl - h + woff[tid >> 6];
    if (tid == 0) lbase[NB] = (unsigned)n;
    __syncthreads();

    // ---- Pass B: stage records into LDS, bucket-sorted ----
    #pragma unroll
    for (int r = 0; r < RPT; ++r) {
        if (meta[r] != 0xFFFFFFFFu) {
            unsigned b    = meta[r] >> 13;
            unsigned rank = meta[r] & 0x1FFFu;
            srec[lbase[b] + rank] = rec[r];
        }
    }
    __syncthreads();

    // ---- Pass C: sequential uint4 writeout + transposed table column ----
    uint4* gout4 = (uint4*)(recs + (size_t)g * RPB);
    for (int p4 = tid; p4 < n / 4; p4 += TPB)
        gout4[p4] = ((const uint4*)srec)[p4];
    for (int p = (n & ~3) + tid; p < n; p += TPB)   // tail (n%4, normally 0)
        recs[(size_t)g * RPB + p] = srec[p];
    for (int b = tid; b < TW; b += TPB)
        tabT[(size_t)b * NBLK + g] = lbase[b];
}

// ---------------------------------------------------------------------------
// Bucket phase: one block per bucket. Bulk-load ALL (s,e) segment bounds for
// this bucket into LDS first (two contiguous ~2.9 KB rows of tabT) -- no
// serial global pointer-chase. Then waves stream the 734 segments (record
// loads across regions are independent -> deeply pipelined), recompute
// w = exp(P*lit), accumulate packed (num,den) via LDS atomics, decode,
// sigmoid + squared error, block-reduce, ONE device atomicAdd into out[0].
// ---------------------------------------------------------------------------
__global__ __launch_bounds__(1024)
void bucket_loss_kernel(const unsigned* __restrict__ recs,
                        const unsigned* __restrict__ tabT,
                        const float* __restrict__ cc,
                        float* __restrict__ out) {
    __shared__ unsigned lacc[CPB];    // 16 KB
    __shared__ unsigned sseg[NBLK];   // 2.9 KB
    __shared__ unsigned eseg[NBLK];   // 2.9 KB
    const int b    = (int)blockIdx.x;
    const int lane = (int)threadIdx.x & 63;
    const int wid  = (int)threadIdx.x >> 6;

    for (int j = threadIdx.x; j < CPB; j += 1024) lacc[j] = 0;
    for (int t = threadIdx.x; t < NBLK; t += 1024) {
        sseg[t] = tabT[(size_t)b       * NBLK + t];
        eseg[t] = tabT[(size_t)(b + 1) * NBLK + t];
    }
    __syncthreads();

    // one wave per partition-block segment; bounds come from LDS
    for (int blk = wid; blk < NBLK; blk += 16) {
        unsigned s = sseg[blk];
        unsigned e = eseg[blk];
        const unsigned* rr = recs + (size_t)blk * RPB;
        for (unsigned k = s + (unsigned)lane; k < e; k += 64) {
            unsigned r   = rr[k];
            float    lit = (float)(r >> 12) * QINV;
            float    w   = __expf(Pc * lit);
            atomicAdd(&lacc[r & 0xFFFu], pack_fx(lit * w, w));
        }
    }
    __syncthreads();

    float v = 0.0f;
    const float* gc = cc + (size_t)b * CPB;
    for (int j = threadIdx.x; j < CPB; j += 1024) {
        unsigned a   = lacc[j];                 // packed fields can't overflow
        float    num = (float)(a & 0xffffu) * FXINV;
        float    den = (float)(a >> 16)     * FXINV;
        float    sm  = 1.0f / (1.0f + __expf(-Ac * (num / den - 0.5f)));
        float    e0  = sm - gc[j];
        v += e0 * e0;
    }
    v *= 1.0f / (float)NUM_CLAUSES;

    #pragma unroll
    for (int off = 32; off > 0; off >>= 1)
        v += __shfl_down(v, off, 64);

    __shared__ float partial[16];   // 1024 threads = 16 waves
    if (lane == 0) partial[wid] = v;
    __syncthreads();
    if (threadIdx.x == 0) {
        float s = 0.f;
        #pragma unroll
        for (int w = 0; w < 16; ++w) s += partial[w];
        atomicAdd(out, s);          // out zeroed by partition block 0
    }
}

// ---------------------------------------------------------------------------
extern "C" void kernel_launch(void* const* d_in, const int* in_sizes, int n_in,
                              void* d_out, int out_size, void* d_ws, size_t ws_size,
                              hipStream_t stream) {
    const float* xv      = (const float*)d_in[0];   // [V] fp32
    const int*   adj_pos = (const int*)  d_in[1];   // [2,E] int32
    const int*   adj_neg = (const int*)  d_in[2];   // [2,E] int32
    const float* cc      = (const float*)d_in[3];   // [C] fp32 (ones)

    char* ws = (char*)d_ws;
    unsigned* recs = (unsigned*)ws;
    unsigned* tabT = (unsigned*)(ws + OFF_TAB);
    float*    out  = (float*)d_out;

    // 1) partition both polarities into per-block bucket-sorted runs
    //    (no global atomics; zeroes out[0])
    partition_kernel<<<NBLK, TPB, 0, stream>>>(adj_pos, adj_neg, xv,
                                               recs, tabT, out);

    // 2) per-bucket segment-gather (LDS-staged bounds) + LDS accumulate +
    //    loss; each block atomic-adds its partial into out[0]
    bucket_loss_kernel<<<NB, 1024, 0, stream>>>(recs, tabT, cc, out);
}

// Round 12
// 146.624 us; speedup vs baseline: 1.0833x; 1.0046x over previous
//
#include <hip/hip_runtime.h>

// Problem constants (match reference file)
constexpr int   NUM_CLAUSES = 1000000;
constexpr int   NUM_EDGES   = 3000000;   // per polarity
constexpr float Pc = 5.0f;
constexpr float Ac = 10.0f;

// Clause-accumulator packing: low 16 bits = num * 2^6, high 16 = den * 2^6.
// Exactly 3 pos + 3 neg edges per clause; each term <= e^5 = 148.413 ->
// max field sum 6*148.413*64 = 56,990 < 65,536: no overflow, no lo->hi carry.
constexpr float FXSCALE = 64.0f;
constexpr float FXINV   = 1.0f / 64.0f;

// Bucketing: 250 buckets x 4000 clauses.
constexpr int NB  = 250;
constexpr int CPB = 4000;            // clauses per bucket (fits 12 bits)

// Partition geometry: 256 threads, 4096 records per block, 16 per thread.
// Small blocks -> 1466-block grid (5.7/CU) + 18 KB LDS (8 blocks/CU limit):
// fixes the 41% occupancy of the 734x512 configuration.
constexpr int TPB   = 256;
constexpr int RPB   = 4096;
constexpr int RPT   = RPB / TPB;     // 16
constexpr int NBLKP = (NUM_EDGES + RPB - 1) / RPB;   // 733 blocks / polarity
constexpr int NBLK  = 2 * NBLKP;     // 1466 partition blocks total
constexpr int TW    = NB + 1;        // table row width (251: scan + total)

// Record format (u32): lit quantized to 20 bits << 12 | local clause (12 bits).
// Polarity already applied to lit, so pos/neg records are interchangeable.
constexpr float QSCALE = 1048575.0f;    // 2^20 - 1
constexpr float QINV   = 1.0f / 1048575.0f;

// Workspace layout (bytes):
//   recs u32[NBLK*RPB] = 24,018,944  @ 0        (block-major, bucket-sorted)
//   tab  u32[NBLK*TW]  =  1,471,864  @ OFF_TAB  (row-major per-block scans;
//                                               sequential writes, (s,e) for
//                                               bucket b are ADJACENT words)
constexpr size_t OFF_TAB = (size_t)NBLK * RPB * sizeof(unsigned);

__device__ __forceinline__ unsigned pack_fx(float num, float den) {
    unsigned lo = (unsigned)(num * FXSCALE + 0.5f);
    unsigned hi = (unsigned)(den * FXSCALE + 0.5f);
    return lo | (hi << 16);
}

// ---------------------------------------------------------------------------
// Partition BOTH polarities' 6M edge records into per-block bucket-sorted
// runs. NO GLOBAL ATOMICS: block g writes its records to recs[g*RPB ...]
// (sequential uint4 stores) and its 251-entry local exclusive scan to
// tab[g*TW ...] (sequential). Block 0 zeroes out[0].
// ---------------------------------------------------------------------------
__global__ __launch_bounds__(TPB)
void partition_kernel(const int*   __restrict__ adj_pos,
                      const int*   __restrict__ adj_neg,
                      const float* __restrict__ x,
                      unsigned* __restrict__ recs,
                      unsigned* __restrict__ tab,
                      float* __restrict__ out) {
    __shared__ unsigned hist[NB];
    __shared__ unsigned lbase[TW];     // local exclusive scan (+ total at [NB])
    __shared__ unsigned srec[RPB];     // 16 KB staging, bucket-sorted
    __shared__ unsigned wsum[TPB / 64];
    __shared__ unsigned woff[TPB / 64];

    const int  g     = (int)blockIdx.x;
    const bool neg   = (g >= NBLKP);
    const int  sblk  = neg ? g - NBLKP : g;
    const int  start = sblk * RPB;
    const int  n     = min(RPB, NUM_EDGES - start);
    const int* crow  = neg ? adj_neg : adj_pos;
    const int* vrow  = crow + NUM_EDGES;
    const int  tid   = (int)threadIdx.x;

    if (g == 0 && tid == 0) out[0] = 0.0f;   // bucket kernel atomic-accumulates

    for (int b = tid; b < NB; b += TPB) hist[b] = 0;
    __syncthreads();

    // ---- Pass A: load adjacency (vectorized), gather x, build records ----
    int cc_[RPT], vv_[RPT];
    if (n == RPB) {
        #pragma unroll
        for (int j = 0; j < RPT / 4; ++j) {
            int4 c4 = ((const int4*)(crow + start))[j * TPB + tid];
            int4 v4 = ((const int4*)(vrow + start))[j * TPB + tid];
            cc_[4*j] = c4.x; cc_[4*j+1] = c4.y; cc_[4*j+2] = c4.z; cc_[4*j+3] = c4.w;
            vv_[4*j] = v4.x; vv_[4*j+1] = v4.y; vv_[4*j+2] = v4.z; vv_[4*j+3] = v4.w;
        }
    } else {
        #pragma unroll
        for (int r = 0; r < RPT; ++r) {
            int pos = 4 * ((r >> 2) * TPB + tid) + (r & 3);
            cc_[r] = (pos < n) ? crow[start + pos] : -1;
            vv_[r] = (pos < n) ? vrow[start + pos] : 0;
        }
    }

    float xv[RPT];
    #pragma unroll
    for (int r = 0; r < RPT; ++r) xv[r] = x[vv_[r]];

    unsigned rec[RPT], meta[RPT];   // meta = b<<13 | rank (0xFFFFFFFF inactive)
    #pragma unroll
    for (int r = 0; r < RPT; ++r) {
        meta[r] = 0xFFFFFFFFu;
        if (cc_[r] >= 0) {
            int   c   = cc_[r];
            int   b   = c / CPB;
            float lit = neg ? (1.0f - xv[r]) : xv[r];
            unsigned q = (unsigned)(lit * QSCALE + 0.5f);
            rec[r] = (q << 12) | (unsigned)(c - b * CPB);
            unsigned rank = atomicAdd(&hist[b], 1u);   // rank within block
            meta[r] = ((unsigned)b << 13) | rank;
        }
    }
    __syncthreads();

    // ---- block-local exclusive scan of hist (wave shuffles) ----
    unsigned h    = (tid < NB) ? hist[tid] : 0u;
    unsigned incl = h;
    #pragma unroll
    for (int off = 1; off < 64; off <<= 1) {
        unsigned t = __shfl_up(incl, off, 64);
        if ((tid & 63) >= off) incl += t;
    }
    if ((tid & 63) == 63) wsum[tid >> 6] = incl;
    __syncthreads();
    if (tid == 0) {
        unsigned a = 0;
        #pragma unroll
        for (int w = 0; w < TPB / 64; ++w) { woff[w] = a; a += wsum[w]; }
    }
    __syncthreads();
    if (tid < NB) lbase[tid] = incl - h + woff[tid >> 6];
    if (tid == 0) lbase[NB] = (unsigned)n;
    __syncthreads();

    // ---- Pass B: stage records into LDS, bucket-sorted ----
    #pragma unroll
    for (int r = 0; r < RPT; ++r) {
        if (meta[r] != 0xFFFFFFFFu) {
            unsigned b    = meta[r] >> 13;
            unsigned rank = meta[r] & 0x1FFFu;
            srec[lbase[b] + rank] = rec[r];
        }
    }
    __syncthreads();

    // ---- Pass C: sequential uint4 writeout + sequential table row ----
    uint4* gout4 = (uint4*)(recs + (size_t)g * RPB);
    for (int p4 = tid; p4 < n / 4; p4 += TPB)
        gout4[p4] = ((const uint4*)srec)[p4];
    for (int p = (n & ~3) + tid; p < n; p += TPB)   // tail (n%4, normally 0)
        recs[(size_t)g * RPB + p] = srec[p];
    unsigned* trow = tab + (size_t)g * TW;
    for (int b = tid; b < TW; b += TPB) trow[b] = lbase[b];
}

// ---------------------------------------------------------------------------
// Bucket phase: one block per bucket. Bulk-load (s,e) bounds for this bucket
// -- ONE independent 8B load per partition block (adjacent words in the
// row-major table, L2-resident) -- into LDS. Then stream the 1466 segments
// at 4 SEGMENTS PER WAVE (16 lanes each; avg segment = 16.4 records, so a
// full wave per segment would idle 75% of lanes). LDS atomics accumulate
// packed (num,den); decode, sigmoid + squared error, block-reduce, one
// device atomicAdd into out[0] (zeroed by partition block 0).
// ---------------------------------------------------------------------------
__global__ __launch_bounds__(1024)
void bucket_loss_kernel(const unsigned* __restrict__ recs,
                        const unsigned* __restrict__ tab,
                        const float* __restrict__ cc,
                        float* __restrict__ out) {
    __shared__ unsigned lacc[CPB];     // 16 KB
    __shared__ uint2    srange[NBLK];  // 11.7 KB: (s,e) per partition block
    const int b    = (int)blockIdx.x;
    const int lane = (int)threadIdx.x & 63;
    const int wid  = (int)threadIdx.x >> 6;

    for (int j = threadIdx.x; j < CPB; j += 1024) lacc[j] = 0;
    for (int t = threadIdx.x; t < NBLK; t += 1024) {
        const unsigned* row = tab + (size_t)t * TW + b;
        srange[t] = make_uint2(row[0], row[1]);    // adjacent -> dwordx2
    }
    __syncthreads();

    // 4 segments per wave, 16 lanes per segment
    const int sub  = lane >> 4;          // 0..3
    const int slan = lane & 15;          // lane within segment
    for (int base = wid * 4; base < NBLK; base += 64) {
        int blk = base + sub;
        unsigned s = 0, e = 0;
        if (blk < NBLK) { uint2 se = srange[blk]; s = se.x; e = se.y; }
        const unsigned* rr = recs + (size_t)blk * RPB;
        for (unsigned k = s + (unsigned)slan; k < e; k += 16) {
            unsigned r   = rr[k];
            float    lit = (float)(r >> 12) * QINV;
            float    w   = __expf(Pc * lit);
            atomicAdd(&lacc[r & 0xFFFu], pack_fx(lit * w, w));
        }
    }
    __syncthreads();

    float v = 0.0f;
    const float* gc = cc + (size_t)b * CPB;
    for (int j = threadIdx.x; j < CPB; j += 1024) {
        unsigned a   = lacc[j];                 // packed fields can't overflow
        float    num = (float)(a & 0xffffu) * FXINV;
        float    den = (float)(a >> 16)     * FXINV;
        float    sm  = 1.0f / (1.0f + __expf(-Ac * (num / den - 0.5f)));
        float    e0  = sm - gc[j];
        v += e0 * e0;
    }
    v *= 1.0f / (float)NUM_CLAUSES;

    #pragma unroll
    for (int off = 32; off > 0; off >>= 1)
        v += __shfl_down(v, off, 64);

    __shared__ float partial[16];   // 1024 threads = 16 waves
    if (lane == 0) partial[wid] = v;
    __syncthreads();
    if (threadIdx.x == 0) {
        float s = 0.f;
        #pragma unroll
        for (int w = 0; w < 16; ++w) s += partial[w];
        atomicAdd(out, s);          // out zeroed by partition block 0
    }
}

// ---------------------------------------------------------------------------
extern "C" void kernel_launch(void* const* d_in, const int* in_sizes, int n_in,
                              void* d_out, int out_size, void* d_ws, size_t ws_size,
                              hipStream_t stream) {
    const float* xv      = (const float*)d_in[0];   // [V] fp32
    const int*   adj_pos = (const int*)  d_in[1];   // [2,E] int32
    const int*   adj_neg = (const int*)  d_in[2];   // [2,E] int32
    const float* cc      = (const float*)d_in[3];   // [C] fp32 (ones)

    char* ws = (char*)d_ws;
    unsigned* recs = (unsigned*)ws;
    unsigned* tab  = (unsigned*)(ws + OFF_TAB);
    float*    out  = (float*)d_out;

    // 1) partition both polarities into per-block bucket-sorted runs
    //    (no global atomics; zeroes out[0])
    partition_kernel<<<NBLK, TPB, 0, stream>>>(adj_pos, adj_neg, xv,
                                               recs, tab, out);

    // 2) per-bucket segment-gather (LDS-staged bounds, 4 segments/wave) +
    //    LDS accumulate + loss; each block atomic-adds into out[0]
    bucket_loss_kernel<<<NB, 1024, 0, stream>>>(recs, tab, cc, out);
}